// Round 10
// baseline (197.286 us; speedup 1.0000x reference)
//
#include <hip/hip_runtime.h>
#include <math.h>

#define B_   64
#define S_   197
#define D_   768
#define H_   12
#define HD_  64
#define M_   (B_ * S_)     // 12608
#define MPAD 12672         // 99*128
#define KE   224           // padded contraction length over s (7*32)
#define BH_  (B_ * H_)     // 768
#define WSZ  ((size_t)D_ * D_)   // 589824

typedef _Float16 half8_t __attribute__((ext_vector_type(8)));
typedef _Float16 half4_t __attribute__((ext_vector_type(4)));
typedef _Float16 half2_t __attribute__((ext_vector_type(2)));
typedef float floatx4 __attribute__((ext_vector_type(4)));

// async global->LDS DMA, 16B per lane; lptr must be wave-uniform (HW adds lane*16)
#define LDS_DMA16(gptr, lptr) \
  __builtin_amdgcn_global_load_lds((const __attribute__((address_space(1))) void*)(gptr), \
                                   (__attribute__((address_space(3))) void*)(lptr), 16, 0, 0)

// counted vmcnt wait + raw barrier, schedule-pinned (rule #18)
#define VMCNT(n) do { asm volatile("s_waitcnt vmcnt(" n ")" ::: "memory"); \
                      __builtin_amdgcn_sched_barrier(0); } while (0)
#define BARRIER() do { __builtin_amdgcn_sched_barrier(0); \
                       __builtin_amdgcn_s_barrier(); \
                       __builtin_amdgcn_sched_barrier(0); } while (0)

// ---------------------------------------------------------------------------
// Prep kernel, 3098 blocks (R7 version, verbatim).
// ---------------------------------------------------------------------------
__global__ __launch_bounds__(256) void prep_y_kernel(
    const float* __restrict__ X,
    const float* __restrict__ Wq, const float* __restrict__ Wk,
    const float* __restrict__ Wv, const float* __restrict__ Wo,
    const float* __restrict__ Ek, const float* __restrict__ Ev,
    _Float16* __restrict__ Xh,
    _Float16* __restrict__ Tcat, _Float16* __restrict__ To,
    float* __restrict__ esumK, float* __restrict__ esumV,
    _Float16* __restrict__ Ybuf)
{
    __shared__ _Float16 smem[KE * 66];   // 29568 B; aliased as f32 tile below
    const int bid = blockIdx.x, tid = threadIdx.x;

    if (bid >= 768 && bid < 3072) {        // weight transpose + convert
        const int idx = bid - 768;
        float (*tile)[33] = (float (*)[33])smem;
        const int z = idx / 576, rem = idx % 576;
        const int bx = rem % 24, by = rem / 24;
        // z: 0->Wk, 1->Wv, 2->Wq (into Tcat), 3->Wo (into To)
        const float* W = (z == 0) ? Wk : (z == 1) ? Wv : (z == 2) ? Wq : Wo;
        _Float16* T = (z < 3) ? (Tcat + (size_t)z * WSZ) : To;
        const int n0 = bx * 32, k0 = by * 32;
        const int r = tid >> 3, c4 = (tid & 7) * 4;
        *(float4*)&tile[r][c4] = *(const float4*)&W[(size_t)(k0 + r) * D_ + n0 + c4];
        __syncthreads();
        half4_t o = { (_Float16)tile[c4 + 0][r], (_Float16)tile[c4 + 1][r],
                      (_Float16)tile[c4 + 2][r], (_Float16)tile[c4 + 3][r] };
        *(half4_t*)&T[(size_t)(n0 + r) * D_ + k0 + c4] = o;
        return;
    }

    if (bid >= 3096) {                     // esum over s of E columns
        const int idx = bid - 3096;
        const float* E = idx ? Ev : Ek;
        float* es = idx ? esumV : esumK;
        if (tid < 64) {
            float acc = 0.f;
            for (int s = 0; s < S_; ++s) acc += E[s * 64 + tid];
            es[tid] = acc;
        }
        return;
    }

    if (bid >= 3072) {                     // zero-pad Xh rows [M_, MPAD)
        const int idx = bid - 3072;
        const half8_t z8 = {};
        *(half8_t*)&Xh[(size_t)M_ * D_ + (size_t)(idx * 256 + tid) * 8] = z8;
        return;
    }

    // ----- Y task: Y[b] = E^T @ X_b, and Xh = f16(X) for this slice -----
    _Float16* Xs = smem;                   // KE x 66 f16 tile of X_b columns
    const int idx = bid;
    const int b = idx / 12, n0 = (idx % 12) * 64;
    const int w = tid >> 6, lane = tid & 63;
    const int l15 = lane & 15, quad = lane >> 4;

    #pragma unroll
    for (int i = 0; i < 7; ++i) {
        const int s = i * 32 + (tid >> 3);
        const int d0 = (tid & 7) * 8;
        float4 v0 = make_float4(0.f, 0.f, 0.f, 0.f), v1 = v0;
        if (s < S_) {                      // guard: don't read past X (M_ rows)
            const float* src = &X[(size_t)(b * S_ + s) * D_ + n0 + d0];
            v0 = *(const float4*)src;
            v1 = *(const float4*)(src + 4);
        }
        const half8_t h8 = { (_Float16)v0.x, (_Float16)v0.y, (_Float16)v0.z,
                             (_Float16)v0.w, (_Float16)v1.x, (_Float16)v1.y,
                             (_Float16)v1.z, (_Float16)v1.w };
        if (s < S_)                        // conv output (was the conv task)
            *(half8_t*)&Xh[(size_t)(b * S_ + s) * D_ + n0 + d0] = h8;
        #pragma unroll
        for (int jj = 0; jj < 4; ++jj) {
            half2_t t2 = { h8[2 * jj], h8[2 * jj + 1] };
            *(half2_t*)&Xs[s * 66 + d0 + 2 * jj] = t2;
        }
    }
    __syncthreads();

    floatx4 acc[2][4] = {};
    #pragma unroll
    for (int k7 = 0; k7 < 7; ++k7) {
        half8_t af[2];
        #pragma unroll
        for (int mi = 0; mi < 2; ++mi) {
            const int row = w * 32 + mi * 16 + l15;      // [0,128)
            const float* Esrc = (row < 64) ? Ek : Ev;
            const int er = row & 63;
            #pragma unroll
            for (int jj = 0; jj < 8; ++jj) {
                const int s = k7 * 32 + quad * 8 + jj;
                af[mi][jj] = (_Float16)((s < S_) ? Esrc[s * 64 + er] : 0.f);
            }
        }
        #pragma unroll
        for (int ni = 0; ni < 4; ++ni) {
            const int sb = k7 * 32 + quad * 8;
            half8_t bf;
            #pragma unroll
            for (int jj = 0; jj < 8; ++jj) bf[jj] = Xs[(sb + jj) * 66 + ni * 16 + l15];
            #pragma unroll
            for (int mi = 0; mi < 2; ++mi)
                acc[mi][ni] = __builtin_amdgcn_mfma_f32_16x16x32_f16(
                    af[mi], bf, acc[mi][ni], 0, 0, 0);
        }
    }

    #pragma unroll
    for (int mi = 0; mi < 2; ++mi)
        #pragma unroll
        for (int ni = 0; ni < 4; ++ni)
            #pragma unroll
            for (int i = 0; i < 4; ++i) {
                const int m_local = w * 32 + mi * 16 + quad * 4 + i;
                const int row = (m_local >> 6) * 4096 + b * 64 + (m_local & 63);
                Ybuf[(size_t)row * D_ + n0 + ni * 16 + l15] = (_Float16)acc[mi][ni][i];
            }
}

// ---------------------------------------------------------------------------
// Shared GEMM pipeline: 128x128 tile, BK=32, THREE 16KB buffers, prefetch
// distance 2, counted vmcnt, one raw barrier per K-step (48KB -> 3 blk/CU).
// FIXED swizzle f(r)=(r>>1)&3: bank slot = 16*(r&1) + 4*(quad^((r>>1)&3));
// bits r&1 and (r>>1)&3 are independent -> 16 lanes spread over 8 bank-quad
// slots exactly 2-way = conflict-free (R8's f(r)=r&3 collapsed to 4 slots).
// ---------------------------------------------------------------------------
#define STG32(BUF, T) \
    { _Pragma("unroll") \
      for (int j = 0; j < 2; ++j) { \
          LDS_DMA16(Abase + (size_t)(j * 16) * D_ + (T) * 32, \
                    &sm[(BUF) * 8192 + w * 1024 + j * 512]); \
          LDS_DMA16(Wbase + (size_t)(j * 16) * D_ + (T) * 32, \
                    &sm[(BUF) * 8192 + 4096 + w * 1024 + j * 512]); \
      } }

#define CMP32(BUF) \
    { half8_t af[4], bf[4]; \
      _Pragma("unroll") \
      for (int i = 0; i < 4; ++i) { \
          const int sa = (quad ^ ((fr >> 1) & 3)) * 8; \
          af[i] = *(const half8_t*)&sm[(BUF) * 8192 + (wm + i * 16 + fr) * 32 + sa]; \
          bf[i] = *(const half8_t*)&sm[(BUF) * 8192 + 4096 + (wn + i * 16 + fr) * 32 + sa]; \
      } \
      _Pragma("unroll") \
      for (int mi = 0; mi < 4; ++mi) \
          _Pragma("unroll") \
          for (int ni = 0; ni < 4; ++ni) \
              acc[mi][ni] = __builtin_amdgcn_mfma_f32_16x16x32_f16( \
                  af[mi], bf[ni], acc[mi][ni], 0, 0, 0); }

#define PIPE24() \
    STG32(0, 0); STG32(1, 1); \
    _Pragma("unroll") \
    for (int t = 0; t < 22; ++t) { \
        VMCNT("4"); BARRIER(); \
        STG32((t + 2) % 3, t + 2); \
        CMP32(t % 3); \
    } \
    VMCNT("4"); BARRIER(); \
    CMP32(1); \
    VMCNT("0"); BARRIER(); \
    CMP32(2);

// ---------------------------------------------------------------------------
// Fused Q + PKV GEMM, 1008 blocks: PIPE24 (BK=32, fixed swizzle, 48KB LDS
// -> 3 blocks/CU, 1008 blocks = 1.3 scheduling rounds vs 2.0 at 64KB).
// Epilogues unchanged (Q/pk row transpose; pv mirrored transpose into pvT).
// ct [0,8704) is disjoint from buffer 2 [16384,24576) read by the final
// CMP32; buffers 0/1 are dead after the last barrier.
// ---------------------------------------------------------------------------
__global__ __launch_bounds__(256) void gemm_qpkv(
    const _Float16* __restrict__ Xh, const _Float16* __restrict__ Ybuf,
    const _Float16* __restrict__ Tcat,
    const float* __restrict__ bq, const float* __restrict__ bk,
    const float* __restrict__ bv,
    const float* __restrict__ esumK, const float* __restrict__ esumV,
    _Float16* __restrict__ Qh, _Float16* __restrict__ pk16,
    _Float16* __restrict__ pvT)
{
    __shared__ _Float16 sm[24576];   // 3 x (A 128x32 | B 128x32) = 48 KB
    const int bid = blockIdx.x;
    const _Float16 *A, *W;
    const float *bias, *esum;
    _Float16* O16;
    int m0, n0, rowb;
    bool pvt = false;
    if (bid < 624) {                 // Q
        const int xcd = bid & 7, t = bid >> 3;
        const int slot = t / 6, j = t - slot * 6;
        const int m_blk = slot * 8 + xcd;
        if (m_blk >= MPAD / 128) return;
        m0 = m_blk * 128; n0 = j * 128; rowb = m0;
        A = Xh; W = Tcat + 2 * WSZ + (size_t)n0 * D_;
        bias = bq; esum = nullptr; O16 = Qh;
    } else {                         // PKV
        const int b2 = bid - 624;
        const int xcd = b2 & 7, t = b2 >> 3;
        const int slot = t / 6, j = t - slot * 6;
        const int m_blk = slot * 8 + xcd;    // [0,64)
        m0 = m_blk * 128; n0 = j * 128;
        const bool pv = (m_blk >= 32);
        pvt = pv;
        rowb = pv ? m0 - 4096 : m0;
        A = Ybuf; W = Tcat + (pv ? WSZ : 0) + (size_t)n0 * D_;
        bias = pv ? bv : bk; esum = pv ? esumV : esumK;
        O16 = pk16;
    }

    const int tid = threadIdx.x;
    const int w = tid >> 6, lane = tid & 63;
    const int fr = lane & 15, quad = lane >> 4;
    const int l2 = lane >> 2;
    const int c8 = ((lane & 3) ^ ((l2 >> 1) & 3)) * 8;   // fixed swizzle
    const int wm = (w >> 1) * 64, wn = (w & 1) * 64;

    const _Float16* Abase = A + (size_t)(m0 + w * 32 + l2) * D_ + c8;
    const _Float16* Wbase = W + (size_t)(w * 32 + l2) * D_ + c8;

    floatx4 acc[4][4] = {};

    PIPE24();

    float bval[4];
    #pragma unroll
    for (int ni = 0; ni < 4; ++ni)
        bval[ni] = bias[n0 + wn + ni * 16 + fr];

    _Float16* ct = &sm[w * 2176];   // 32 x 68, within [0,8704)

    if (pvt) {
        // mirrored transpose: ct[n_local][m_local], halves over n
        #pragma unroll
        for (int half = 0; half < 2; ++half) {
            #pragma unroll
            for (int ni2 = 0; ni2 < 2; ++ni2) {
                const int ni = half * 2 + ni2;
                #pragma unroll
                for (int mi = 0; mi < 4; ++mi) {
                    const float4 es4 = *(const float4*)&esum[mi * 16 + quad * 4];
                    const float esv[4] = { es4.x, es4.y, es4.z, es4.w };
                    #pragma unroll
                    for (int i = 0; i < 4; ++i)
                        ct[(ni2 * 16 + fr) * 68 + mi * 16 + quad * 4 + i] =
                            (_Float16)(acc[mi][ni][i] + esv[i] * bval[ni]);
                }
            }
            #pragma unroll
            for (int pass = 0; pass < 4; ++pass) {
                const int rr = pass * 8 + (lane >> 3);    // 32 n-rows
                const int cc = (lane & 7) * 8;            // 64 m-cols
                const half8_t v = *(const half8_t*)&ct[rr * 68 + cc];
                *(half8_t*)&pvT[(size_t)(n0 + wn + half * 32 + rr) * 4096
                                + rowb + wm + cc] = v;
            }
        }
        return;
    }

    // Q / pk: two-pass wave-private LDS transpose + half8 row stores
    #pragma unroll
    for (int half = 0; half < 2; ++half) {
        #pragma unroll
        for (int mi2 = 0; mi2 < 2; ++mi2) {
            const int mi = half * 2 + mi2;
            float esv[4] = {1.f, 1.f, 1.f, 1.f};
            if (esum) {
                const float4 es4 = *(const float4*)&esum[mi * 16 + quad * 4];
                esv[0] = es4.x; esv[1] = es4.y; esv[2] = es4.z; esv[3] = es4.w;
            }
            #pragma unroll
            for (int ni = 0; ni < 4; ++ni)
                #pragma unroll
                for (int i = 0; i < 4; ++i)
                    ct[(mi2 * 16 + quad * 4 + i) * 68 + ni * 16 + fr] =
                        (_Float16)(acc[mi][ni][i] + esv[i] * bval[ni]);
        }
        #pragma unroll
        for (int pass = 0; pass < 4; ++pass) {
            const int rr = pass * 8 + (lane >> 3);
            const int cc = (lane & 7) * 8;
            const half8_t v = *(const half8_t*)&ct[rr * 68 + cc];
            *(half8_t*)&O16[(size_t)(rowb + wm + half * 32 + rr) * D_ + n0 + wn + cc] = v;
        }
    }
}

// ---------------------------------------------------------------------------
// O-projection GEMM: PIPE24 with the fixed swizzle (48KB -> 3 blocks/CU;
// all 594 working blocks co-resident).
// ---------------------------------------------------------------------------
__global__ __launch_bounds__(256) void gemm_o(
    const _Float16* __restrict__ CTX, const _Float16* __restrict__ To,
    const float* __restrict__ bo, float* __restrict__ O32)
{
    __shared__ _Float16 sm[24576];
    const int xcd = blockIdx.x & 7, t = blockIdx.x >> 3;
    const int slot = t / 6, j = t - slot * 6;
    const int m_blk = slot * 8 + xcd;
    if (m_blk >= MPAD / 128) return;
    const int m0 = m_blk * 128, n0 = j * 128;

    const int tid = threadIdx.x;
    const int w = tid >> 6, lane = tid & 63;
    const int fr = lane & 15, quad = lane >> 4;
    const int l2 = lane >> 2;
    const int c8 = ((lane & 3) ^ ((l2 >> 1) & 3)) * 8;   // fixed swizzle
    const int wm = (w >> 1) * 64, wn = (w & 1) * 64;

    const _Float16* Abase = CTX + (size_t)(m0 + w * 32 + l2) * D_ + c8;
    const _Float16* Wbase = To + (size_t)(n0 + w * 32 + l2) * D_ + c8;

    floatx4 acc[4][4] = {};

    PIPE24();

    float bval[4];
    #pragma unroll
    for (int ni = 0; ni < 4; ++ni)
        bval[ni] = bo[n0 + wn + ni * 16 + fr];

    const bool full = (m0 + 128 <= M_);
    #pragma unroll
    for (int ni = 0; ni < 4; ++ni) {
        const int n = n0 + wn + ni * 16 + fr;
        #pragma unroll
        for (int mi = 0; mi < 4; ++mi)
            #pragma unroll
            for (int i = 0; i < 4; ++i) {
                const int m = m0 + wm + mi * 16 + quad * 4 + i;
                if (full || m < M_)
                    O32[(size_t)m * D_ + n] = acc[mi][ni][i] + bval[ni];
            }
    }
}

// ---------------------------------------------------------------------------
// MFMA attention (R9 version, verbatim: pvT b128 loads + T5 setprio).
// ---------------------------------------------------------------------------
__global__ __launch_bounds__(256) void attn_kernel(
    const _Float16* __restrict__ Qh, const _Float16* __restrict__ pk16,
    const _Float16* __restrict__ pvT, _Float16* __restrict__ CTXh)
{
    __shared__ _Float16 P[64 * 80];
    const int bh = blockIdx.x, b = bh / H_, h = bh % H_;
    const int tid = threadIdx.x, w = tid >> 6, lane = tid & 63;
    const int l15 = lane & 15, quad = lane >> 4;
    const _Float16* pkB = pk16 + (size_t)(b * 64) * D_ + h * 64;
    const _Float16* pvB = pvT + (size_t)(h * 64) * 4096 + b * 64;
    const size_t qbase = (size_t)(b * S_) * D_ + h * HD_;

    half8_t bkf[4][2], bvf[4][2];
    #pragma unroll
    for (int ni = 0; ni < 4; ++ni)
        #pragma unroll
        for (int kk = 0; kk < 2; ++kk) {
            bkf[ni][kk] = *(const half8_t*)&pkB[(size_t)(ni * 16 + l15) * D_ + kk * 32 + quad * 8];
            bvf[ni][kk] = *(const half8_t*)&pvB[(size_t)(ni * 16 + l15) * 4096 + kk * 32 + quad * 8];
        }

    for (int t = w; t < 13; t += 4) {
        const int srow = t * 16;
        floatx4 acc[4] = {};
        __builtin_amdgcn_s_setprio(1);
        #pragma unroll
        for (int kk = 0; kk < 2; ++kk) {
            const half8_t aq = *(const half8_t*)
                &Qh[qbase + (size_t)(srow + l15) * D_ + kk * 32 + quad * 8];
            #pragma unroll
            for (int ni = 0; ni < 4; ++ni)
                acc[ni] = __builtin_amdgcn_mfma_f32_16x16x32_f16(
                    aq, bkf[ni][kk], acc[ni], 0, 0, 0);
        }
        __builtin_amdgcn_s_setprio(0);
        float p[4][4];
        #pragma unroll
        for (int i = 0; i < 4; ++i) {
            const float s0 = acc[0][i] * 0.125f, s1 = acc[1][i] * 0.125f;
            const float s2 = acc[2][i] * 0.125f, s3 = acc[3][i] * 0.125f;
            float mx = fmaxf(fmaxf(s0, s1), fmaxf(s2, s3));
            #pragma unroll
            for (int off = 1; off < 16; off <<= 1)
                mx = fmaxf(mx, __shfl_xor(mx, off, 64));
            const float e0 = __expf(s0 - mx), e1 = __expf(s1 - mx);
            const float e2 = __expf(s2 - mx), e3 = __expf(s3 - mx);
            float sme = e0 + e1 + e2 + e3;
            #pragma unroll
            for (int off = 1; off < 16; off <<= 1)
                sme += __shfl_xor(sme, off, 64);
            const float inv = 1.f / sme;
            p[0][i] = e0 * inv; p[1][i] = e1 * inv;
            p[2][i] = e2 * inv; p[3][i] = e3 * inv;
        }
        #pragma unroll
        for (int ni = 0; ni < 4; ++ni)
            #pragma unroll
            for (int i = 0; i < 4; ++i)
                P[(w * 16 + quad * 4 + i) * 80 + ni * 16 + l15] = (_Float16)p[ni][i];

        floatx4 accv[4] = {};
        __builtin_amdgcn_s_setprio(1);
        #pragma unroll
        for (int kk = 0; kk < 2; ++kk) {
            const half8_t ap = *(const half8_t*)&P[(w * 16 + l15) * 80 + kk * 32 + quad * 8];
            #pragma unroll
            for (int ni = 0; ni < 4; ++ni)
                accv[ni] = __builtin_amdgcn_mfma_f32_16x16x32_f16(
                    ap, bvf[ni][kk], accv[ni], 0, 0, 0);
        }
        __builtin_amdgcn_s_setprio(0);
        #pragma unroll
        for (int ni = 0; ni < 4; ++ni)
            #pragma unroll
            for (int i = 0; i < 4; ++i) {
                const int s = srow + quad * 4 + i;
                if (s < S_)
                    CTXh[qbase + (size_t)s * D_ + ni * 16 + l15] = (_Float16)accv[ni][i];
            }
    }
}

// ---------------------------------------------------------------------------
extern "C" void kernel_launch(void* const* d_in, const int* in_sizes, int n_in,
                              void* d_out, int out_size, void* d_ws, size_t ws_size,
                              hipStream_t stream) {
    const float* X   = (const float*)d_in[0];
    const float* Wq  = (const float*)d_in[1];
    const float* bq  = (const float*)d_in[2];
    const float* Wk  = (const float*)d_in[3];
    const float* bk  = (const float*)d_in[4];
    const float* Wv  = (const float*)d_in[5];
    const float* bv  = (const float*)d_in[6];
    const float* Wo  = (const float*)d_in[7];
    const float* bo  = (const float*)d_in[8];
    const float* E_k = (const float*)d_in[9];
    const float* E_v = (const float*)d_in[10];
    float* out = (float*)d_out;

    char* p = (char*)d_ws;
    _Float16* Xh   = (_Float16*)p; p += (size_t)MPAD * D_ * 2;   // reused as CTXh
    _Float16* Tcat = (_Float16*)p; p += (size_t)3 * WSZ * 2;     // Wk,Wv,Wq
    _Float16* To   = (_Float16*)p; p += (size_t)WSZ * 2;
    _Float16* Qh   = (_Float16*)p; p += (size_t)MPAD * D_ * 2;
    float* esumK   = (float*)p;    p += 64 * sizeof(float);
    float* esumV   = (float*)p;    p += 64 * sizeof(float);
    _Float16* Ybuf = (_Float16*)p; p += (size_t)8192 * D_ * 2;
    _Float16* pk16 = (_Float16*)p; p += (size_t)4096 * D_ * 2;
    _Float16* pvT  = (_Float16*)p;   // [768][4096] f16

    prep_y_kernel<<<3098, 256, 0, stream>>>(X, Wq, Wk, Wv, Wo, E_k, E_v,
                                            Xh, Tcat, To, esumK, esumV, Ybuf);
    gemm_qpkv<<<1008, 256, 0, stream>>>(Xh, Ybuf, Tcat,
                                        bq, bk, bv, esumK, esumV,
                                        Qh, pk16, pvT);
    attn_kernel<<<BH_, 256, 0, stream>>>(Qh, pk16, pvT, Xh);
    gemm_o<<<624, 256, 0, stream>>>(Xh, To, bo, out);
}

// Round 11
// 193.189 us; speedup vs baseline: 1.0212x; 1.0212x over previous
//
#include <hip/hip_runtime.h>
#include <math.h>

#define B_   64
#define S_   197
#define D_   768
#define H_   12
#define HD_  64
#define M_   (B_ * S_)     // 12608
#define MPAD 12672         // 99*128
#define KE   224           // padded contraction length over s (7*32)
#define BH_  (B_ * H_)     // 768
#define WSZ  ((size_t)D_ * D_)   // 589824

typedef _Float16 half8_t __attribute__((ext_vector_type(8)));
typedef _Float16 half4_t __attribute__((ext_vector_type(4)));
typedef _Float16 half2_t __attribute__((ext_vector_type(2)));
typedef float floatx4 __attribute__((ext_vector_type(4)));

// async global->LDS DMA, 16B per lane; lptr must be wave-uniform (HW adds lane*16)
#define LDS_DMA16(gptr, lptr) \
  __builtin_amdgcn_global_load_lds((const __attribute__((address_space(1))) void*)(gptr), \
                                   (__attribute__((address_space(3))) void*)(lptr), 16, 0, 0)

// counted vmcnt wait + raw barrier, schedule-pinned (rule #18)
#define VMCNT(n) do { asm volatile("s_waitcnt vmcnt(" n ")" ::: "memory"); \
                      __builtin_amdgcn_sched_barrier(0); } while (0)
#define BARRIER() do { __builtin_amdgcn_sched_barrier(0); \
                       __builtin_amdgcn_s_barrier(); \
                       __builtin_amdgcn_sched_barrier(0); } while (0)

// ---------------------------------------------------------------------------
// Prep kernel, 3098 blocks (R7/R10 version, verbatim).
// ---------------------------------------------------------------------------
__global__ __launch_bounds__(256) void prep_y_kernel(
    const float* __restrict__ X,
    const float* __restrict__ Wq, const float* __restrict__ Wk,
    const float* __restrict__ Wv, const float* __restrict__ Wo,
    const float* __restrict__ Ek, const float* __restrict__ Ev,
    _Float16* __restrict__ Xh,
    _Float16* __restrict__ Tcat, _Float16* __restrict__ To,
    float* __restrict__ esumK, float* __restrict__ esumV,
    _Float16* __restrict__ Ybuf)
{
    __shared__ _Float16 smem[KE * 66];   // 29568 B; aliased as f32 tile below
    const int bid = blockIdx.x, tid = threadIdx.x;

    if (bid >= 768 && bid < 3072) {        // weight transpose + convert
        const int idx = bid - 768;
        float (*tile)[33] = (float (*)[33])smem;
        const int z = idx / 576, rem = idx % 576;
        const int bx = rem % 24, by = rem / 24;
        // z: 0->Wk, 1->Wv, 2->Wq (into Tcat), 3->Wo (into To)
        const float* W = (z == 0) ? Wk : (z == 1) ? Wv : (z == 2) ? Wq : Wo;
        _Float16* T = (z < 3) ? (Tcat + (size_t)z * WSZ) : To;
        const int n0 = bx * 32, k0 = by * 32;
        const int r = tid >> 3, c4 = (tid & 7) * 4;
        *(float4*)&tile[r][c4] = *(const float4*)&W[(size_t)(k0 + r) * D_ + n0 + c4];
        __syncthreads();
        half4_t o = { (_Float16)tile[c4 + 0][r], (_Float16)tile[c4 + 1][r],
                      (_Float16)tile[c4 + 2][r], (_Float16)tile[c4 + 3][r] };
        *(half4_t*)&T[(size_t)(n0 + r) * D_ + k0 + c4] = o;
        return;
    }

    if (bid >= 3096) {                     // esum over s of E columns
        const int idx = bid - 3096;
        const float* E = idx ? Ev : Ek;
        float* es = idx ? esumV : esumK;
        if (tid < 64) {
            float acc = 0.f;
            for (int s = 0; s < S_; ++s) acc += E[s * 64 + tid];
            es[tid] = acc;
        }
        return;
    }

    if (bid >= 3072) {                     // zero-pad Xh rows [M_, MPAD)
        const int idx = bid - 3072;
        const half8_t z8 = {};
        *(half8_t*)&Xh[(size_t)M_ * D_ + (size_t)(idx * 256 + tid) * 8] = z8;
        return;
    }

    // ----- Y task: Y[b] = E^T @ X_b, and Xh = f16(X) for this slice -----
    _Float16* Xs = smem;                   // KE x 66 f16 tile of X_b columns
    const int idx = bid;
    const int b = idx / 12, n0 = (idx % 12) * 64;
    const int w = tid >> 6, lane = tid & 63;
    const int l15 = lane & 15, quad = lane >> 4;

    #pragma unroll
    for (int i = 0; i < 7; ++i) {
        const int s = i * 32 + (tid >> 3);
        const int d0 = (tid & 7) * 8;
        float4 v0 = make_float4(0.f, 0.f, 0.f, 0.f), v1 = v0;
        if (s < S_) {                      // guard: don't read past X (M_ rows)
            const float* src = &X[(size_t)(b * S_ + s) * D_ + n0 + d0];
            v0 = *(const float4*)src;
            v1 = *(const float4*)(src + 4);
        }
        const half8_t h8 = { (_Float16)v0.x, (_Float16)v0.y, (_Float16)v0.z,
                             (_Float16)v0.w, (_Float16)v1.x, (_Float16)v1.y,
                             (_Float16)v1.z, (_Float16)v1.w };
        if (s < S_)                        // conv output (was the conv task)
            *(half8_t*)&Xh[(size_t)(b * S_ + s) * D_ + n0 + d0] = h8;
        #pragma unroll
        for (int jj = 0; jj < 4; ++jj) {
            half2_t t2 = { h8[2 * jj], h8[2 * jj + 1] };
            *(half2_t*)&Xs[s * 66 + d0 + 2 * jj] = t2;
        }
    }
    __syncthreads();

    floatx4 acc[2][4] = {};
    #pragma unroll
    for (int k7 = 0; k7 < 7; ++k7) {
        half8_t af[2];
        #pragma unroll
        for (int mi = 0; mi < 2; ++mi) {
            const int row = w * 32 + mi * 16 + l15;      // [0,128)
            const float* Esrc = (row < 64) ? Ek : Ev;
            const int er = row & 63;
            #pragma unroll
            for (int jj = 0; jj < 8; ++jj) {
                const int s = k7 * 32 + quad * 8 + jj;
                af[mi][jj] = (_Float16)((s < S_) ? Esrc[s * 64 + er] : 0.f);
            }
        }
        #pragma unroll
        for (int ni = 0; ni < 4; ++ni) {
            const int sb = k7 * 32 + quad * 8;
            half8_t bf;
            #pragma unroll
            for (int jj = 0; jj < 8; ++jj) bf[jj] = Xs[(sb + jj) * 66 + ni * 16 + l15];
            #pragma unroll
            for (int mi = 0; mi < 2; ++mi)
                acc[mi][ni] = __builtin_amdgcn_mfma_f32_16x16x32_f16(
                    af[mi], bf, acc[mi][ni], 0, 0, 0);
        }
    }

    #pragma unroll
    for (int mi = 0; mi < 2; ++mi)
        #pragma unroll
        for (int ni = 0; ni < 4; ++ni)
            #pragma unroll
            for (int i = 0; i < 4; ++i) {
                const int m_local = w * 32 + mi * 16 + quad * 4 + i;
                const int row = (m_local >> 6) * 4096 + b * 64 + (m_local & 63);
                Ybuf[(size_t)row * D_ + n0 + ni * 16 + l15] = (_Float16)acc[mi][ni][i];
            }
}

// ---------------------------------------------------------------------------
// Fused Q + PKV GEMM (R9 form -- its best measured total): 128x128, BK=64,
// 2-phase __syncthreads dbuf, conflict-free 8-chunk XOR swizzle.
// Epilogues: Q/pk row transpose; pv mirrored transpose into pvT.
// ---------------------------------------------------------------------------
__global__ __launch_bounds__(256) void gemm_qpkv(
    const _Float16* __restrict__ Xh, const _Float16* __restrict__ Ybuf,
    const _Float16* __restrict__ Tcat,
    const float* __restrict__ bq, const float* __restrict__ bk,
    const float* __restrict__ bv,
    const float* __restrict__ esumK, const float* __restrict__ esumV,
    _Float16* __restrict__ Qh, _Float16* __restrict__ pk16,
    _Float16* __restrict__ pvT)
{
    __shared__ _Float16 sm[32768];   // 2 x (A 128x64 | B 128x64) = 64 KB
    const int bid = blockIdx.x;
    const _Float16 *A, *W;
    const float *bias, *esum;
    _Float16* O16;
    int m0, n0, rowb;
    bool pvt = false;
    if (bid < 624) {                 // Q
        const int xcd = bid & 7, t = bid >> 3;
        const int slot = t / 6, j = t - slot * 6;
        const int m_blk = slot * 8 + xcd;
        if (m_blk >= MPAD / 128) return;
        m0 = m_blk * 128; n0 = j * 128; rowb = m0;
        A = Xh; W = Tcat + 2 * WSZ + (size_t)n0 * D_;
        bias = bq; esum = nullptr; O16 = Qh;
    } else {                         // PKV
        const int b2 = bid - 624;
        const int xcd = b2 & 7, t = b2 >> 3;
        const int slot = t / 6, j = t - slot * 6;
        const int m_blk = slot * 8 + xcd;    // [0,64)
        m0 = m_blk * 128; n0 = j * 128;
        const bool pv = (m_blk >= 32);
        pvt = pv;
        rowb = pv ? m0 - 4096 : m0;
        A = Ybuf; W = Tcat + (pv ? WSZ : 0) + (size_t)n0 * D_;
        bias = pv ? bv : bk; esum = pv ? esumV : esumK;
        O16 = pk16;
    }

    const int tid = threadIdx.x;
    const int w = tid >> 6, lane = tid & 63;
    const int fr = lane & 15, quad = lane >> 4, f7 = lane & 7;
    const int l3 = lane >> 3;
    const int csrc = ((lane & 7) ^ l3) * 8;
    const int wm = (w >> 1) * 64, wn = (w & 1) * 64;

    const _Float16* Abase = A + (size_t)(m0 + w * 32 + l3) * D_ + csrc;
    const _Float16* Wbase = W + (size_t)(w * 32 + l3) * D_ + csrc;

    floatx4 acc[4][4] = {};

#define QPKV_STAGE(BUF, K0) \
    { _Pragma("unroll") \
      for (int j = 0; j < 4; ++j) { \
          LDS_DMA16(Abase + (size_t)(j * 8) * D_ + (K0), &sm[(BUF) * 16384 + w * 2048 + j * 512]); \
          LDS_DMA16(Wbase + (size_t)(j * 8) * D_ + (K0), &sm[(BUF) * 16384 + 8192 + w * 2048 + j * 512]); \
      } }

#define QPKV_COMPUTE(BUF) \
    { _Pragma("unroll") \
      for (int ksub = 0; ksub < 2; ++ksub) { \
          const int sa = ((ksub * 4 + quad) ^ f7) * 8; \
          half8_t af[4], bf[4]; \
          _Pragma("unroll") \
          for (int i = 0; i < 4; ++i) { \
              af[i] = *(const half8_t*)&sm[(BUF) * 16384 + (wm + i * 16 + fr) * 64 + sa]; \
              bf[i] = *(const half8_t*)&sm[(BUF) * 16384 + 8192 + (wn + i * 16 + fr) * 64 + sa]; \
          } \
          _Pragma("unroll") \
          for (int mi = 0; mi < 4; ++mi) \
              _Pragma("unroll") \
              for (int ni = 0; ni < 4; ++ni) \
                  acc[mi][ni] = __builtin_amdgcn_mfma_f32_16x16x32_f16( \
                      af[mi], bf[ni], acc[mi][ni], 0, 0, 0); \
      } }

    QPKV_STAGE(0, 0);
    __syncthreads();
    #pragma unroll
    for (int t = 0; t < 10; t += 2) {
        QPKV_STAGE(1, (t + 1) * 64);
        QPKV_COMPUTE(0);
        __syncthreads();
        QPKV_STAGE(0, (t + 2) * 64);
        QPKV_COMPUTE(1);
        __syncthreads();
    }
    QPKV_STAGE(1, 11 * 64);
    QPKV_COMPUTE(0);
    __syncthreads();
    QPKV_COMPUTE(1);   // final tile lives in buffer 1: [16384,32768), disjoint from ct

    float bval[4];
    #pragma unroll
    for (int ni = 0; ni < 4; ++ni)
        bval[ni] = bias[n0 + wn + ni * 16 + fr];

    _Float16* ct = &sm[w * 2176];   // 32 x 68, within [0,8704) -- buffer 0 region

    if (pvt) {
        // mirrored transpose: ct[n_local][m_local], halves over n
        #pragma unroll
        for (int half = 0; half < 2; ++half) {
            #pragma unroll
            for (int ni2 = 0; ni2 < 2; ++ni2) {
                const int ni = half * 2 + ni2;
                #pragma unroll
                for (int mi = 0; mi < 4; ++mi) {
                    const float4 es4 = *(const float4*)&esum[mi * 16 + quad * 4];
                    const float esv[4] = { es4.x, es4.y, es4.z, es4.w };
                    #pragma unroll
                    for (int i = 0; i < 4; ++i)
                        ct[(ni2 * 16 + fr) * 68 + mi * 16 + quad * 4 + i] =
                            (_Float16)(acc[mi][ni][i] + esv[i] * bval[ni]);
                }
            }
            #pragma unroll
            for (int pass = 0; pass < 4; ++pass) {
                const int rr = pass * 8 + (lane >> 3);    // 32 n-rows
                const int cc = (lane & 7) * 8;            // 64 m-cols
                const half8_t v = *(const half8_t*)&ct[rr * 68 + cc];
                *(half8_t*)&pvT[(size_t)(n0 + wn + half * 32 + rr) * 4096
                                + rowb + wm + cc] = v;
            }
        }
        return;
    }

    // Q / pk: two-pass wave-private LDS transpose + half8 row stores
    #pragma unroll
    for (int half = 0; half < 2; ++half) {
        #pragma unroll
        for (int mi2 = 0; mi2 < 2; ++mi2) {
            const int mi = half * 2 + mi2;
            float esv[4] = {1.f, 1.f, 1.f, 1.f};
            if (esum) {
                const float4 es4 = *(const float4*)&esum[mi * 16 + quad * 4];
                esv[0] = es4.x; esv[1] = es4.y; esv[2] = es4.z; esv[3] = es4.w;
            }
            #pragma unroll
            for (int ni = 0; ni < 4; ++ni)
                #pragma unroll
                for (int i = 0; i < 4; ++i)
                    ct[(mi2 * 16 + quad * 4 + i) * 68 + ni * 16 + fr] =
                        (_Float16)(acc[mi][ni][i] + esv[i] * bval[ni]);
        }
        #pragma unroll
        for (int pass = 0; pass < 4; ++pass) {
            const int rr = pass * 8 + (lane >> 3);
            const int cc = (lane & 7) * 8;
            const half8_t v = *(const half8_t*)&ct[rr * 68 + cc];
            *(half8_t*)&O16[(size_t)(rowb + wm + half * 32 + rr) * D_ + n0 + wn + cc] = v;
        }
    }
}

// ---------------------------------------------------------------------------
// O-projection GEMM (R10 form): 128x128, BK=32, THREE 16KB buffers,
// prefetch distance 2, counted vmcnt, one raw barrier per K-step, fixed
// conflict-free swizzle f(r)=(r>>1)&3 (48KB -> 3 blocks/CU; all 594
// working blocks co-resident).  NEW: T5 setprio around the MFMA cluster
// (PIPE24's stage/compute role-split is the regime where setprio pays).
// ---------------------------------------------------------------------------
#define STG32(BUF, T) \
    { _Pragma("unroll") \
      for (int j = 0; j < 2; ++j) { \
          LDS_DMA16(Abase + (size_t)(j * 16) * D_ + (T) * 32, \
                    &sm[(BUF) * 8192 + w * 1024 + j * 512]); \
          LDS_DMA16(Wbase + (size_t)(j * 16) * D_ + (T) * 32, \
                    &sm[(BUF) * 8192 + 4096 + w * 1024 + j * 512]); \
      } }

#define CMP32(BUF) \
    { half8_t af[4], bf[4]; \
      _Pragma("unroll") \
      for (int i = 0; i < 4; ++i) { \
          const int sa = (quad ^ ((fr >> 1) & 3)) * 8; \
          af[i] = *(const half8_t*)&sm[(BUF) * 8192 + (wm + i * 16 + fr) * 32 + sa]; \
          bf[i] = *(const half8_t*)&sm[(BUF) * 8192 + 4096 + (wn + i * 16 + fr) * 32 + sa]; \
      } \
      __builtin_amdgcn_s_setprio(1); \
      _Pragma("unroll") \
      for (int mi = 0; mi < 4; ++mi) \
          _Pragma("unroll") \
          for (int ni = 0; ni < 4; ++ni) \
              acc[mi][ni] = __builtin_amdgcn_mfma_f32_16x16x32_f16( \
                  af[mi], bf[ni], acc[mi][ni], 0, 0, 0); \
      __builtin_amdgcn_s_setprio(0); }

#define PIPE24() \
    STG32(0, 0); STG32(1, 1); \
    _Pragma("unroll") \
    for (int t = 0; t < 22; ++t) { \
        VMCNT("4"); BARRIER(); \
        STG32((t + 2) % 3, t + 2); \
        CMP32(t % 3); \
    } \
    VMCNT("4"); BARRIER(); \
    CMP32(1); \
    VMCNT("0"); BARRIER(); \
    CMP32(2);

__global__ __launch_bounds__(256) void gemm_o(
    const _Float16* __restrict__ CTX, const _Float16* __restrict__ To,
    const float* __restrict__ bo, float* __restrict__ O32)
{
    __shared__ _Float16 sm[24576];
    const int xcd = blockIdx.x & 7, t = blockIdx.x >> 3;
    const int slot = t / 6, j = t - slot * 6;
    const int m_blk = slot * 8 + xcd;
    if (m_blk >= MPAD / 128) return;
    const int m0 = m_blk * 128, n0 = j * 128;

    const int tid = threadIdx.x;
    const int w = tid >> 6, lane = tid & 63;
    const int fr = lane & 15, quad = lane >> 4;
    const int l2 = lane >> 2;
    const int c8 = ((lane & 3) ^ ((l2 >> 1) & 3)) * 8;   // fixed swizzle
    const int wm = (w >> 1) * 64, wn = (w & 1) * 64;

    const _Float16* Abase = CTX + (size_t)(m0 + w * 32 + l2) * D_ + c8;
    const _Float16* Wbase = To + (size_t)(n0 + w * 32 + l2) * D_ + c8;

    floatx4 acc[4][4] = {};

    PIPE24();

    float bval[4];
    #pragma unroll
    for (int ni = 0; ni < 4; ++ni)
        bval[ni] = bo[n0 + wn + ni * 16 + fr];

    const bool full = (m0 + 128 <= M_);
    #pragma unroll
    for (int ni = 0; ni < 4; ++ni) {
        const int n = n0 + wn + ni * 16 + fr;
        #pragma unroll
        for (int mi = 0; mi < 4; ++mi)
            #pragma unroll
            for (int i = 0; i < 4; ++i) {
                const int m = m0 + wm + mi * 16 + quad * 4 + i;
                if (full || m < M_)
                    O32[(size_t)m * D_ + n] = acc[mi][ni][i] + bval[ni];
            }
    }
}

// ---------------------------------------------------------------------------
// MFMA attention (R9/R10 version, verbatim: pvT b128 loads + T5 setprio).
// ---------------------------------------------------------------------------
__global__ __launch_bounds__(256) void attn_kernel(
    const _Float16* __restrict__ Qh, const _Float16* __restrict__ pk16,
    const _Float16* __restrict__ pvT, _Float16* __restrict__ CTXh)
{
    __shared__ _Float16 P[64 * 80];
    const int bh = blockIdx.x, b = bh / H_, h = bh % H_;
    const int tid = threadIdx.x, w = tid >> 6, lane = tid & 63;
    const int l15 = lane & 15, quad = lane >> 4;
    const _Float16* pkB = pk16 + (size_t)(b * 64) * D_ + h * 64;
    const _Float16* pvB = pvT + (size_t)(h * 64) * 4096 + b * 64;
    const size_t qbase = (size_t)(b * S_) * D_ + h * HD_;

    half8_t bkf[4][2], bvf[4][2];
    #pragma unroll
    for (int ni = 0; ni < 4; ++ni)
        #pragma unroll
        for (int kk = 0; kk < 2; ++kk) {
            bkf[ni][kk] = *(const half8_t*)&pkB[(size_t)(ni * 16 + l15) * D_ + kk * 32 + quad * 8];
            bvf[ni][kk] = *(const half8_t*)&pvB[(size_t)(ni * 16 + l15) * 4096 + kk * 32 + quad * 8];
        }

    for (int t = w; t < 13; t += 4) {
        const int srow = t * 16;
        floatx4 acc[4] = {};
        __builtin_amdgcn_s_setprio(1);
        #pragma unroll
        for (int kk = 0; kk < 2; ++kk) {
            const half8_t aq = *(const half8_t*)
                &Qh[qbase + (size_t)(srow + l15) * D_ + kk * 32 + quad * 8];
            #pragma unroll
            for (int ni = 0; ni < 4; ++ni)
                acc[ni] = __builtin_amdgcn_mfma_f32_16x16x32_f16(
                    aq, bkf[ni][kk], acc[ni], 0, 0, 0);
        }
        __builtin_amdgcn_s_setprio(0);
        float p[4][4];
        #pragma unroll
        for (int i = 0; i < 4; ++i) {
            const float s0 = acc[0][i] * 0.125f, s1 = acc[1][i] * 0.125f;
            const float s2 = acc[2][i] * 0.125f, s3 = acc[3][i] * 0.125f;
            float mx = fmaxf(fmaxf(s0, s1), fmaxf(s2, s3));
            #pragma unroll
            for (int off = 1; off < 16; off <<= 1)
                mx = fmaxf(mx, __shfl_xor(mx, off, 64));
            const float e0 = __expf(s0 - mx), e1 = __expf(s1 - mx);
            const float e2 = __expf(s2 - mx), e3 = __expf(s3 - mx);
            float sme = e0 + e1 + e2 + e3;
            #pragma unroll
            for (int off = 1; off < 16; off <<= 1)
                sme += __shfl_xor(sme, off, 64);
            const float inv = 1.f / sme;
            p[0][i] = e0 * inv; p[1][i] = e1 * inv;
            p[2][i] = e2 * inv; p[3][i] = e3 * inv;
        }
        #pragma unroll
        for (int ni = 0; ni < 4; ++ni)
            #pragma unroll
            for (int i = 0; i < 4; ++i)
                P[(w * 16 + quad * 4 + i) * 80 + ni * 16 + l15] = (_Float16)p[ni][i];

        floatx4 accv[4] = {};
        __builtin_amdgcn_s_setprio(1);
        #pragma unroll
        for (int kk = 0; kk < 2; ++kk) {
            const half8_t ap = *(const half8_t*)&P[(w * 16 + l15) * 80 + kk * 32 + quad * 8];
            #pragma unroll
            for (int ni = 0; ni < 4; ++ni)
                accv[ni] = __builtin_amdgcn_mfma_f32_16x16x32_f16(
                    ap, bvf[ni][kk], accv[ni], 0, 0, 0);
        }
        __builtin_amdgcn_s_setprio(0);
        #pragma unroll
        for (int ni = 0; ni < 4; ++ni)
            #pragma unroll
            for (int i = 0; i < 4; ++i) {
                const int s = srow + quad * 4 + i;
                if (s < S_)
                    CTXh[qbase + (size_t)s * D_ + ni * 16 + l15] = (_Float16)accv[ni][i];
            }
    }
}

// ---------------------------------------------------------------------------
extern "C" void kernel_launch(void* const* d_in, const int* in_sizes, int n_in,
                              void* d_out, int out_size, void* d_ws, size_t ws_size,
                              hipStream_t stream) {
    const float* X   = (const float*)d_in[0];
    const float* Wq  = (const float*)d_in[1];
    const float* bq  = (const float*)d_in[2];
    const float* Wk  = (const float*)d_in[3];
    const float* bk  = (const float*)d_in[4];
    const float* Wv  = (const float*)d_in[5];
    const float* bv  = (const float*)d_in[6];
    const float* Wo  = (const float*)d_in[7];
    const float* bo  = (const float*)d_in[8];
    const float* E_k = (const float*)d_in[9];
    const float* E_v = (const float*)d_in[10];
    float* out = (float*)d_out;

    char* p = (char*)d_ws;
    _Float16* Xh   = (_Float16*)p; p += (size_t)MPAD * D_ * 2;   // reused as CTXh
    _Float16* Tcat = (_Float16*)p; p += (size_t)3 * WSZ * 2;     // Wk,Wv,Wq
    _Float16* To   = (_Float16*)p; p += (size_t)WSZ * 2;
    _Float16* Qh   = (_Float16*)p; p += (size_t)MPAD * D_ * 2;
    float* esumK   = (float*)p;    p += 64 * sizeof(float);
    float* esumV   = (float*)p;    p += 64 * sizeof(float);
    _Float16* Ybuf = (_Float16*)p; p += (size_t)8192 * D_ * 2;
    _Float16* pk16 = (_Float16*)p; p += (size_t)4096 * D_ * 2;
    _Float16* pvT  = (_Float16*)p;   // [768][4096] f16

    prep_y_kernel<<<3098, 256, 0, stream>>>(X, Wq, Wk, Wv, Wo, E_k, E_v,
                                            Xh, Tcat, To, esumK, esumV, Ybuf);
    gemm_qpkv<<<1008, 256, 0, stream>>>(Xh, Ybuf, Tcat,
                                        bq, bk, bv, esumK, esumV,
                                        Qh, pk16, pvT);
    attn_kernel<<<BH_, 256, 0, stream>>>(Qh, pk16, pvT, Xh);
    gemm_o<<<624, 256, 0, stream>>>(Xh, To, bo, out);
}